// Round 3
// baseline (928.089 us; speedup 1.0000x reference)
//
#include <hip/hip_runtime.h>

typedef unsigned int u32;
typedef unsigned short u16;
typedef __attribute__((ext_vector_type(8))) short s16x8;
typedef __attribute__((ext_vector_type(4))) float f32x4;
typedef __attribute__((ext_vector_type(4))) unsigned int u32x4;

#define TBL    524288u
#define TMASK  (TBL - 1u)
#define HPRIME 2654435761u

// res[l] = floor(16 * 1.3819^l); dense (linear) while (res+1)^2 <= 2^19 -> levels 0..11
__device__ constexpr int RESI[16] = {16,22,30,42,58,80,111,153,212,294,406,561,775,1072,1481,2047};

static __device__ __forceinline__ u16 f2bf(float f){            // RNE f32->bf16
  u32 u = __builtin_bit_cast(u32, f);
  return (u16)((u + 0x7fffu + ((u >> 16) & 1u)) >> 16);
}
static __device__ __forceinline__ float bf2f(u16 h){ return __builtin_bit_cast(float, (u32)h << 16); }
static __device__ __forceinline__ u32 plo(u32 a, u32 b){ return (a & 0xffffu) | (b << 16); }         // (lo16 a, lo16 b)
static __device__ __forceinline__ u32 phi(u32 a, u32 b){ return (a >> 16) | (b & 0xffff0000u); }     // (hi16 a, hi16 b)

#define MFMA(A,B,C) __builtin_amdgcn_mfma_f32_16x16x32_bf16((A),(B),(C),0,0,0)

// Fused instant-NGP: fp32 hash-grid encode (per-thread) + 34->64->64->3 MLP via bf16-split MFMA.
// x,y enter layer 1 through the fp32 C operand (no bf16 loss on the dominant input);
// layers 2/3 use hi/lo bf16 splits of both activations and weights (rel err ~2^-17).
// All LDS regions are wave-private -> no __syncthreads anywhere.
// launch_bounds(256,4): VGPR 120<=128, LDS 39936<=40960 -> 4 blocks/CU (R2: 2 blocks/CU
// gave Occupancy 20.6%, VALUBusy 28%, 2.9 TB/s fill -> latency-bound, so double waves).
__global__ __launch_bounds__(256, 4) void ngp_fused(
    const float2* __restrict__ xq,   // [N] (x,y) fp32
    const float2* __restrict__ tab,  // [16*2^19] (f0,f1) fp32
    const float*  __restrict__ w1,   // [34][64]
    const float*  __restrict__ w2,   // [64][64]
    const float*  __restrict__ w3,   // [64][3]
    float* __restrict__ out,         // [N][3]
    int iters)
{
  __shared__ __align__(16) u16   encS[256 * 40];   // 32 bf16 features + 8 pad (80 B stride)
  __shared__ __align__(16) float xyS [256 * 2];    // fp32 x,y per point
  __shared__ __align__(16) u32   hS  [4][16 * 68]; // per-wave 16x64 (hi|lo) u32, stride 68 (+4 pad)

  const int tid  = threadIdx.x;
  const int lane = tid & 63;
  const int wv   = tid >> 6;
  const int m    = lane & 15;   // A row / B,C col
  const int q    = lane >> 4;   // k-quad

  // ---- build B-frags from global fp32 weights (one-time; L2-cached) ----
  float w1x[4], w1y[4];
  s16x8 B1[4], B2h[4][2], B2l[4][2], B3h[2], B3l[2];
  #pragma unroll
  for (int c = 0; c < 4; ++c) {
    const int n = c*16 + m;
    w1x[c] = w1[n]; w1y[c] = w1[64 + n];
    s16x8 f1;
    #pragma unroll
    for (int j = 0; j < 8; ++j) {               // B1: feature rows 2..33, K=32 exactly
      const int k = q*8 + j;
      f1[j] = (short)f2bf(w1[(2 + k)*64 + n]);
    }
    B1[c] = f1;
    #pragma unroll
    for (int s = 0; s < 2; ++s) {
      s16x8 fh, fl;
      #pragma unroll
      for (int j = 0; j < 8; ++j) {
        const int k = s*32 + q*8 + j;
        const float v = w2[k*64 + n];
        const u16 h = f2bf(v);
        fh[j] = (short)h; fl[j] = (short)f2bf(v - bf2f(h));
      }
      B2h[c][s] = fh; B2l[c][s] = fl;
    }
  }
  #pragma unroll
  for (int s = 0; s < 2; ++s) {
    s16x8 fh, fl;
    #pragma unroll
    for (int j = 0; j < 8; ++j) {
      const int k = s*32 + q*8 + j;
      const float v = (m < 3) ? w3[k*3 + m] : 0.f;
      const u16 h = f2bf(v);
      fh[j] = (short)h; fl[j] = (short)f2bf(v - bf2f(h));
    }
    B3h[s] = fh; B3l[s] = fl;
  }

  for (int it = 0; it < iters; ++it) {
    const int base = (blockIdx.x * iters + it) << 8;   // 256 points / iteration

    // ---- phase A: per-thread fp32 encode -> bf16 feature row in LDS ----
    {
      const float2 xy = xq[base + tid];
      ((float2*)xyS)[tid] = xy;
      const float xf = xy.x, yf = xy.y;
      u32 er[16];
      #pragma unroll
      for (int l = 0; l < 16; ++l) {
        const int res = RESI[l];
        const float px = xf * (float)res, py = yf * (float)res;
        const float fx = floorf(px), fy = floorf(py);
        const float wx = px - fx, wy = py - fy;
        const u32 ix = (u32)fx, iy = (u32)fy;
        const float2* t = tab + (size_t)l * TBL;
        u32 i00, i10, i01, i11;
        if (l < 12) {                                  // dense linear index
          const u32 st = (u32)res + 1u;
          i00 = ix + iy*st; i10 = i00 + 1u; i01 = i00 + st; i11 = i01 + 1u;
        } else {                                       // spatial hash, u32 wraparound
          const u32 hy = iy * HPRIME, hy1 = hy + HPRIME;
          i00 = ( ix        ^ hy ) & TMASK;
          i10 = ((ix + 1u)  ^ hy ) & TMASK;
          i01 = ( ix        ^ hy1) & TMASK;
          i11 = ((ix + 1u)  ^ hy1) & TMASK;
        }
        const float2 e00 = t[i00], e10 = t[i10], e01 = t[i01], e11 = t[i11];
        const float w00 = (1.f-wx)*(1.f-wy), w10 = wx*(1.f-wy);
        const float w01 = (1.f-wx)*wy,       w11 = wx*wy;
        const float f0 = e00.x*w00 + e10.x*w10 + e01.x*w01 + e11.x*w11;
        const float f1 = e00.y*w00 + e10.y*w10 + e01.y*w01 + e11.y*w11;
        er[l] = (u32)f2bf(f0) | ((u32)f2bf(f1) << 16);
      }
      uint4* rowp = (uint4*)&encS[tid * 40];
      rowp[0] = make_uint4(er[0],  er[1],  er[2],  er[3]);
      rowp[1] = make_uint4(er[4],  er[5],  er[6],  er[7]);
      rowp[2] = make_uint4(er[8],  er[9],  er[10], er[11]);
      rowp[3] = make_uint4(er[12], er[13], er[14], er[15]);
    }

    // ---- phase B: per-wave MFMA MLP, 4 tiles of 16 points (wave-private, no barriers) ----
    #pragma unroll 1
    for (int t4 = 0; t4 < 4; ++t4) {
      const int rbase = wv*64 + t4*16;
      const s16x8 a1 = *(const s16x8*)&encS[(rbase + m)*40 + q*8];

      float xr[4], yr[4];
      #pragma unroll
      for (int r = 0; r < 4; ++r) {
        const float2 v = ((const float2*)xyS)[rbase + q*4 + r];
        xr[r] = v.x; yr[r] = v.y;
      }

      f32x4 acc[4];
      #pragma unroll
      for (int c = 0; c < 4; ++c) {
        f32x4 z;
        #pragma unroll
        for (int r = 0; r < 4; ++r) z[r] = xr[r]*w1x[c] + yr[r]*w1y[c];  // fp32 x,y path
        acc[c] = MFMA(a1, B1[c], z);
      }

      u32* hw = &hS[wv][0];
      #pragma unroll
      for (int c = 0; c < 4; ++c)
        #pragma unroll
        for (int r = 0; r < 4; ++r) {
          const float h = fmaxf(acc[c][r], 0.f);
          const u16 hi = f2bf(h);
          const u16 lo = f2bf(h - bf2f(hi));
          hw[(q*4 + r)*68 + c*16 + m] = (u32)hi | ((u32)lo << 16);
        }

      uint4 r0 = *(uint4*)&hw[m*68 + q*8];
      uint4 r1 = *(uint4*)&hw[m*68 + q*8 + 4];
      uint4 r2 = *(uint4*)&hw[m*68 + 32 + q*8];
      uint4 r3 = *(uint4*)&hw[m*68 + 32 + q*8 + 4];
      u32x4 t0, t1;
      t0.x=plo(r0.x,r0.y); t0.y=plo(r0.z,r0.w); t0.z=plo(r1.x,r1.y); t0.w=plo(r1.z,r1.w);
      s16x8 hi0 = __builtin_bit_cast(s16x8, t0);
      t1.x=phi(r0.x,r0.y); t1.y=phi(r0.z,r0.w); t1.z=phi(r1.x,r1.y); t1.w=phi(r1.z,r1.w);
      s16x8 lo0 = __builtin_bit_cast(s16x8, t1);
      t0.x=plo(r2.x,r2.y); t0.y=plo(r2.z,r2.w); t0.z=plo(r3.x,r3.y); t0.w=plo(r3.z,r3.w);
      s16x8 hi1 = __builtin_bit_cast(s16x8, t0);
      t1.x=phi(r2.x,r2.y); t1.y=phi(r2.z,r2.w); t1.z=phi(r3.x,r3.y); t1.w=phi(r3.z,r3.w);
      s16x8 lo1 = __builtin_bit_cast(s16x8, t1);

      #pragma unroll
      for (int c = 0; c < 4; ++c) {
        f32x4 z = {0.f,0.f,0.f,0.f};
        z = MFMA(hi0, B2h[c][0], z); z = MFMA(hi1, B2h[c][1], z);
        z = MFMA(lo0, B2h[c][0], z); z = MFMA(lo1, B2h[c][1], z);
        z = MFMA(hi0, B2l[c][0], z); z = MFMA(hi1, B2l[c][1], z);
        acc[c] = z;
      }

      #pragma unroll
      for (int c = 0; c < 4; ++c)
        #pragma unroll
        for (int r = 0; r < 4; ++r) {
          const float h = fmaxf(acc[c][r], 0.f);
          const u16 hi = f2bf(h);
          const u16 lo = f2bf(h - bf2f(hi));
          hw[(q*4 + r)*68 + c*16 + m] = (u32)hi | ((u32)lo << 16);
        }

      r0 = *(uint4*)&hw[m*68 + q*8];
      r1 = *(uint4*)&hw[m*68 + q*8 + 4];
      r2 = *(uint4*)&hw[m*68 + 32 + q*8];
      r3 = *(uint4*)&hw[m*68 + 32 + q*8 + 4];
      t0.x=plo(r0.x,r0.y); t0.y=plo(r0.z,r0.w); t0.z=plo(r1.x,r1.y); t0.w=plo(r1.z,r1.w);
      hi0 = __builtin_bit_cast(s16x8, t0);
      t1.x=phi(r0.x,r0.y); t1.y=phi(r0.z,r0.w); t1.z=phi(r1.x,r1.y); t1.w=phi(r1.z,r1.w);
      lo0 = __builtin_bit_cast(s16x8, t1);
      t0.x=plo(r2.x,r2.y); t0.y=plo(r2.z,r2.w); t0.z=plo(r3.x,r3.y); t0.w=plo(r3.z,r3.w);
      hi1 = __builtin_bit_cast(s16x8, t0);
      t1.x=phi(r2.x,r2.y); t1.y=phi(r2.z,r2.w); t1.z=phi(r3.x,r3.y); t1.w=phi(r3.z,r3.w);
      lo1 = __builtin_bit_cast(s16x8, t1);

      f32x4 z = {0.f,0.f,0.f,0.f};
      z = MFMA(hi0, B3h[0], z); z = MFMA(hi1, B3h[1], z);
      z = MFMA(lo0, B3h[0], z); z = MFMA(lo1, B3h[1], z);
      z = MFMA(hi0, B3l[0], z); z = MFMA(hi1, B3l[1], z);

      if (m < 3) {   // C: row = q*4+r, col = m
        #pragma unroll
        for (int r = 0; r < 4; ++r)
          out[(size_t)(base + rbase + q*4 + r)*3 + m] = z[r];
      }
    }
  }
}

extern "C" void kernel_launch(void* const* d_in, const int* in_sizes, int n_in,
                              void* d_out, int out_size, void* d_ws, size_t ws_size,
                              hipStream_t stream) {
  const int N = in_sizes[0] / 2;            // 2^21 points
  const int ITERS = 4;
  const int blocks = N / (256 * ITERS);     // 2048 blocks
  ngp_fused<<<blocks, 256, 0, stream>>>(
      (const float2*)d_in[0], (const float2*)d_in[1],
      (const float*)d_in[2], (const float*)d_in[3], (const float*)d_in[4],
      (float*)d_out, ITERS);
}

// Round 4
// 795.200 us; speedup vs baseline: 1.1671x; 1.1671x over previous
//
#include <hip/hip_runtime.h>

typedef unsigned int u32;
typedef unsigned short u16;
typedef __attribute__((ext_vector_type(8))) short s16x8;
typedef __attribute__((ext_vector_type(4))) float f32x4;
typedef __attribute__((ext_vector_type(4))) unsigned int u32x4;

#define TBL    524288u
#define TMASK  (TBL - 1u)
#define HPRIME 2654435761u

// res[l] = floor(16 * 1.3819^l); dense (linear) while (res+1)^2 <= 2^19 -> levels 0..11
__device__ constexpr int RESI[16] = {16,22,30,42,58,80,111,153,212,294,406,561,775,1072,1481,2047};

static __device__ __forceinline__ u16 f2bf(float f){            // RNE f32->bf16
  u32 u = __builtin_bit_cast(u32, f);
  return (u16)((u + 0x7fffu + ((u >> 16) & 1u)) >> 16);
}
static __device__ __forceinline__ float bf2f(u16 h){ return __builtin_bit_cast(float, (u32)h << 16); }
static __device__ __forceinline__ u32 plo(u32 a, u32 b){ return (a & 0xffffu) | (b << 16); }         // (lo16 a, lo16 b)
static __device__ __forceinline__ u32 phi(u32 a, u32 b){ return (a >> 16) | (b & 0xffff0000u); }     // (hi16 a, hi16 b)

#define MFMA(A,B,C) __builtin_amdgcn_mfma_f32_16x16x32_bf16((A),(B),(C),0,0,0)

// Fused instant-NGP: fp32 hash-grid encode (per-thread) + 34->64->64->3 MLP via bf16-split MFMA.
// x,y enter layer 1 through the fp32 C operand; layers 2/3 use hi/lo bf16 splits (~2^-17 rel err).
// All LDS regions are wave-private -> no __syncthreads anywhere.
// OCCUPANCY HISTORY (do not "optimize" blindly):
//   (256,2): VGPR 120, no spill, 515 us, Occ 20.6%   (R2)
//   (256,4): allocator squeezed to 64 VGPR -> weight frags spilled to scratch,
//            WRITE_SIZE 27->344 MB, FETCH +1.1 GB, 928 us                  (R3)
//   (256,3): budget ~170 VGPR -> natural 120 fits, 3 blocks/CU, LDS 117/160 KB. (this round)
__global__ __launch_bounds__(256, 3) void ngp_fused(
    const float2* __restrict__ xq,   // [N] (x,y) fp32
    const float2* __restrict__ tab,  // [16*2^19] (f0,f1) fp32
    const float*  __restrict__ w1,   // [34][64]
    const float*  __restrict__ w2,   // [64][64]
    const float*  __restrict__ w3,   // [64][3]
    float* __restrict__ out,         // [N][3]
    int iters)
{
  __shared__ __align__(16) u16   encS[256 * 40];   // 32 bf16 features + 8 pad (80 B stride)
  __shared__ __align__(16) float xyS [256 * 2];    // fp32 x,y per point
  __shared__ __align__(16) u32   hS  [4][16 * 68]; // per-wave 16x64 (hi|lo) u32, stride 68 (+4 pad)

  const int tid  = threadIdx.x;
  const int lane = tid & 63;
  const int wv   = tid >> 6;
  const int m    = lane & 15;   // A row / B,C col
  const int q    = lane >> 4;   // k-quad

  // ---- build B-frags from global fp32 weights (one-time; L2-cached) ----
  float w1x[4], w1y[4];
  s16x8 B1[4], B2h[4][2], B2l[4][2], B3h[2], B3l[2];
  #pragma unroll
  for (int c = 0; c < 4; ++c) {
    const int n = c*16 + m;
    w1x[c] = w1[n]; w1y[c] = w1[64 + n];
    s16x8 f1;
    #pragma unroll
    for (int j = 0; j < 8; ++j) {               // B1: feature rows 2..33, K=32 exactly
      const int k = q*8 + j;
      f1[j] = (short)f2bf(w1[(2 + k)*64 + n]);
    }
    B1[c] = f1;
    #pragma unroll
    for (int s = 0; s < 2; ++s) {
      s16x8 fh, fl;
      #pragma unroll
      for (int j = 0; j < 8; ++j) {
        const int k = s*32 + q*8 + j;
        const float v = w2[k*64 + n];
        const u16 h = f2bf(v);
        fh[j] = (short)h; fl[j] = (short)f2bf(v - bf2f(h));
      }
      B2h[c][s] = fh; B2l[c][s] = fl;
    }
  }
  #pragma unroll
  for (int s = 0; s < 2; ++s) {
    s16x8 fh, fl;
    #pragma unroll
    for (int j = 0; j < 8; ++j) {
      const int k = s*32 + q*8 + j;
      const float v = (m < 3) ? w3[k*3 + m] : 0.f;
      const u16 h = f2bf(v);
      fh[j] = (short)h; fl[j] = (short)f2bf(v - bf2f(h));
    }
    B3h[s] = fh; B3l[s] = fl;
  }

  for (int it = 0; it < iters; ++it) {
    const int base = (blockIdx.x * iters + it) << 8;   // 256 points / iteration

    // ---- phase A: per-thread fp32 encode -> bf16 feature row in LDS ----
    {
      const float2 xy = xq[base + tid];
      ((float2*)xyS)[tid] = xy;
      const float xf = xy.x, yf = xy.y;
      u32 er[16];
      #pragma unroll
      for (int l = 0; l < 16; ++l) {
        const int res = RESI[l];
        const float px = xf * (float)res, py = yf * (float)res;
        const float fx = floorf(px), fy = floorf(py);
        const float wx = px - fx, wy = py - fy;
        const u32 ix = (u32)fx, iy = (u32)fy;
        const float2* t = tab + (size_t)l * TBL;
        u32 i00, i10, i01, i11;
        if (l < 12) {                                  // dense linear index
          const u32 st = (u32)res + 1u;
          i00 = ix + iy*st; i10 = i00 + 1u; i01 = i00 + st; i11 = i01 + 1u;
        } else {                                       // spatial hash, u32 wraparound
          const u32 hy = iy * HPRIME, hy1 = hy + HPRIME;
          i00 = ( ix        ^ hy ) & TMASK;
          i10 = ((ix + 1u)  ^ hy ) & TMASK;
          i01 = ( ix        ^ hy1) & TMASK;
          i11 = ((ix + 1u)  ^ hy1) & TMASK;
        }
        const float2 e00 = t[i00], e10 = t[i10], e01 = t[i01], e11 = t[i11];
        const float w00 = (1.f-wx)*(1.f-wy), w10 = wx*(1.f-wy);
        const float w01 = (1.f-wx)*wy,       w11 = wx*wy;
        const float f0 = e00.x*w00 + e10.x*w10 + e01.x*w01 + e11.x*w11;
        const float f1 = e00.y*w00 + e10.y*w10 + e01.y*w01 + e11.y*w11;
        er[l] = (u32)f2bf(f0) | ((u32)f2bf(f1) << 16);
      }
      uint4* rowp = (uint4*)&encS[tid * 40];
      rowp[0] = make_uint4(er[0],  er[1],  er[2],  er[3]);
      rowp[1] = make_uint4(er[4],  er[5],  er[6],  er[7]);
      rowp[2] = make_uint4(er[8],  er[9],  er[10], er[11]);
      rowp[3] = make_uint4(er[12], er[13], er[14], er[15]);
    }

    // ---- phase B: per-wave MFMA MLP, 4 tiles of 16 points (wave-private, no barriers) ----
    #pragma unroll 1
    for (int t4 = 0; t4 < 4; ++t4) {
      const int rbase = wv*64 + t4*16;
      const s16x8 a1 = *(const s16x8*)&encS[(rbase + m)*40 + q*8];

      float xr[4], yr[4];
      #pragma unroll
      for (int r = 0; r < 4; ++r) {
        const float2 v = ((const float2*)xyS)[rbase + q*4 + r];
        xr[r] = v.x; yr[r] = v.y;
      }

      f32x4 acc[4];
      #pragma unroll
      for (int c = 0; c < 4; ++c) {
        f32x4 z;
        #pragma unroll
        for (int r = 0; r < 4; ++r) z[r] = xr[r]*w1x[c] + yr[r]*w1y[c];  // fp32 x,y path
        acc[c] = MFMA(a1, B1[c], z);
      }

      u32* hw = &hS[wv][0];
      #pragma unroll
      for (int c = 0; c < 4; ++c)
        #pragma unroll
        for (int r = 0; r < 4; ++r) {
          const float h = fmaxf(acc[c][r], 0.f);
          const u16 hi = f2bf(h);
          const u16 lo = f2bf(h - bf2f(hi));
          hw[(q*4 + r)*68 + c*16 + m] = (u32)hi | ((u32)lo << 16);
        }

      uint4 r0 = *(uint4*)&hw[m*68 + q*8];
      uint4 r1 = *(uint4*)&hw[m*68 + q*8 + 4];
      uint4 r2 = *(uint4*)&hw[m*68 + 32 + q*8];
      uint4 r3 = *(uint4*)&hw[m*68 + 32 + q*8 + 4];
      u32x4 t0, t1;
      t0.x=plo(r0.x,r0.y); t0.y=plo(r0.z,r0.w); t0.z=plo(r1.x,r1.y); t0.w=plo(r1.z,r1.w);
      s16x8 hi0 = __builtin_bit_cast(s16x8, t0);
      t1.x=phi(r0.x,r0.y); t1.y=phi(r0.z,r0.w); t1.z=phi(r1.x,r1.y); t1.w=phi(r1.z,r1.w);
      s16x8 lo0 = __builtin_bit_cast(s16x8, t1);
      t0.x=plo(r2.x,r2.y); t0.y=plo(r2.z,r2.w); t0.z=plo(r3.x,r3.y); t0.w=plo(r3.z,r3.w);
      s16x8 hi1 = __builtin_bit_cast(s16x8, t0);
      t1.x=phi(r2.x,r2.y); t1.y=phi(r2.z,r2.w); t1.z=phi(r3.x,r3.y); t1.w=phi(r3.z,r3.w);
      s16x8 lo1 = __builtin_bit_cast(s16x8, t1);

      #pragma unroll
      for (int c = 0; c < 4; ++c) {
        f32x4 z = {0.f,0.f,0.f,0.f};
        z = MFMA(hi0, B2h[c][0], z); z = MFMA(hi1, B2h[c][1], z);
        z = MFMA(lo0, B2h[c][0], z); z = MFMA(lo1, B2h[c][1], z);
        z = MFMA(hi0, B2l[c][0], z); z = MFMA(hi1, B2l[c][1], z);
        acc[c] = z;
      }

      #pragma unroll
      for (int c = 0; c < 4; ++c)
        #pragma unroll
        for (int r = 0; r < 4; ++r) {
          const float h = fmaxf(acc[c][r], 0.f);
          const u16 hi = f2bf(h);
          const u16 lo = f2bf(h - bf2f(hi));
          hw[(q*4 + r)*68 + c*16 + m] = (u32)hi | ((u32)lo << 16);
        }

      r0 = *(uint4*)&hw[m*68 + q*8];
      r1 = *(uint4*)&hw[m*68 + q*8 + 4];
      r2 = *(uint4*)&hw[m*68 + 32 + q*8];
      r3 = *(uint4*)&hw[m*68 + 32 + q*8 + 4];
      t0.x=plo(r0.x,r0.y); t0.y=plo(r0.z,r0.w); t0.z=plo(r1.x,r1.y); t0.w=plo(r1.z,r1.w);
      hi0 = __builtin_bit_cast(s16x8, t0);
      t1.x=phi(r0.x,r0.y); t1.y=phi(r0.z,r0.w); t1.z=phi(r1.x,r1.y); t1.w=phi(r1.z,r1.w);
      lo0 = __builtin_bit_cast(s16x8, t1);
      t0.x=plo(r2.x,r2.y); t0.y=plo(r2.z,r2.w); t0.z=plo(r3.x,r3.y); t0.w=plo(r3.z,r3.w);
      hi1 = __builtin_bit_cast(s16x8, t0);
      t1.x=phi(r2.x,r2.y); t1.y=phi(r2.z,r2.w); t1.z=phi(r3.x,r3.y); t1.w=phi(r3.z,r3.w);
      lo1 = __builtin_bit_cast(s16x8, t1);

      f32x4 z = {0.f,0.f,0.f,0.f};
      z = MFMA(hi0, B3h[0], z); z = MFMA(hi1, B3h[1], z);
      z = MFMA(lo0, B3h[0], z); z = MFMA(lo1, B3h[1], z);
      z = MFMA(hi0, B3l[0], z); z = MFMA(hi1, B3l[1], z);

      if (m < 3) {   // C: row = q*4+r, col = m
        #pragma unroll
        for (int r = 0; r < 4; ++r)
          out[(size_t)(base + rbase + q*4 + r)*3 + m] = z[r];
      }
    }
  }
}

extern "C" void kernel_launch(void* const* d_in, const int* in_sizes, int n_in,
                              void* d_out, int out_size, void* d_ws, size_t ws_size,
                              hipStream_t stream) {
  const int N = in_sizes[0] / 2;            // 2^21 points
  const int ITERS = 4;
  const int blocks = N / (256 * ITERS);     // 2048 blocks
  ngp_fused<<<blocks, 256, 0, stream>>>(
      (const float2*)d_in[0], (const float2*)d_in[1],
      (const float*)d_in[2], (const float*)d_in[3], (const float*)d_in[4],
      (float*)d_out, ITERS);
}

// Round 5
// 532.895 us; speedup vs baseline: 1.7416x; 1.4922x over previous
//
#include <hip/hip_runtime.h>

typedef unsigned int u32;
typedef unsigned short u16;
typedef __attribute__((ext_vector_type(8))) short s16x8;
typedef __attribute__((ext_vector_type(4))) float f32x4;
typedef __attribute__((ext_vector_type(4))) unsigned int u32x4;
typedef float f32x4a __attribute__((ext_vector_type(4), aligned(8)));  // 8B-aligned float4 load

#define TBL    524288u
#define TMASK  (TBL - 1u)
#define HPRIME 2654435761u

// res[l] = floor(16 * 1.3819^l); dense (linear) while (res+1)^2 <= 2^19 -> levels 0..11
__device__ constexpr int RESI[16] = {16,22,30,42,58,80,111,153,212,294,406,561,775,1072,1481,2047};

static __device__ __forceinline__ u16 f2bf(float f){            // RNE f32->bf16
  u32 u = __builtin_bit_cast(u32, f);
  return (u16)((u + 0x7fffu + ((u >> 16) & 1u)) >> 16);
}
static __device__ __forceinline__ float bf2f(u16 h){ return __builtin_bit_cast(float, (u32)h << 16); }
static __device__ __forceinline__ u32 plo(u32 a, u32 b){ return (a & 0xffffu) | (b << 16); }         // (lo16 a, lo16 b)
static __device__ __forceinline__ u32 phi(u32 a, u32 b){ return (a >> 16) | (b & 0xffff0000u); }     // (hi16 a, hi16 b)

#define MFMA(A,B,C) __builtin_amdgcn_mfma_f32_16x16x32_bf16((A),(B),(C),0,0,0)

// Fused instant-NGP: fp32 hash-grid encode (per-thread) + 34->64->64->3 MLP via bf16-split MFMA.
// x,y enter layer 1 through the fp32 C operand; layers 2/3 use hi/lo bf16 splits (~2^-17 rel err).
// All LDS regions are wave-private -> no __syncthreads anywhere.
// OCCUPANCY HISTORY (do not "optimize" blindly):
//   (256,2): VGPR 120, no spill, 515 us, Occ 20.6%                          (R2 - keep)
//   (256,4): squeezed to 64 VGPR -> frag spills, WRITE 27->344 MB, 928 us    (R3 - dead end)
//   (256,3): squeezed to 84 VGPR -> still spills, WRITE 329 MB, 795 us       (R4 - dead end)
// The ~104 resident weight-frag VGPRs mean >2 blocks/CU always spills. Stay at (256,2).
// R5 change: dense-level corner pairs (e00,e10)/(e01,e11) are contiguous float2s ->
// one float4 load each. Gathers/pt: 64 -> 40 (TCP tag-lookup serialization is the bottleneck).
__global__ __launch_bounds__(256, 2) void ngp_fused(
    const float2* __restrict__ xq,   // [N] (x,y) fp32
    const float2* __restrict__ tab,  // [16*2^19] (f0,f1) fp32
    const float*  __restrict__ w1,   // [34][64]
    const float*  __restrict__ w2,   // [64][64]
    const float*  __restrict__ w3,   // [64][3]
    float* __restrict__ out,         // [N][3]
    int iters)
{
  __shared__ __align__(16) u16   encS[256 * 40];   // 32 bf16 features + 8 pad (80 B stride)
  __shared__ __align__(16) float xyS [256 * 2];    // fp32 x,y per point
  __shared__ __align__(16) u32   hS  [4][16 * 68]; // per-wave 16x64 (hi|lo) u32, stride 68 (+4 pad)

  const int tid  = threadIdx.x;
  const int lane = tid & 63;
  const int wv   = tid >> 6;
  const int m    = lane & 15;   // A row / B,C col
  const int q    = lane >> 4;   // k-quad

  // ---- build B-frags from global fp32 weights (one-time; L2-cached) ----
  float w1x[4], w1y[4];
  s16x8 B1[4], B2h[4][2], B2l[4][2], B3h[2], B3l[2];
  #pragma unroll
  for (int c = 0; c < 4; ++c) {
    const int n = c*16 + m;
    w1x[c] = w1[n]; w1y[c] = w1[64 + n];
    s16x8 f1;
    #pragma unroll
    for (int j = 0; j < 8; ++j) {               // B1: feature rows 2..33, K=32 exactly
      const int k = q*8 + j;
      f1[j] = (short)f2bf(w1[(2 + k)*64 + n]);
    }
    B1[c] = f1;
    #pragma unroll
    for (int s = 0; s < 2; ++s) {
      s16x8 fh, fl;
      #pragma unroll
      for (int j = 0; j < 8; ++j) {
        const int k = s*32 + q*8 + j;
        const float v = w2[k*64 + n];
        const u16 h = f2bf(v);
        fh[j] = (short)h; fl[j] = (short)f2bf(v - bf2f(h));
      }
      B2h[c][s] = fh; B2l[c][s] = fl;
    }
  }
  #pragma unroll
  for (int s = 0; s < 2; ++s) {
    s16x8 fh, fl;
    #pragma unroll
    for (int j = 0; j < 8; ++j) {
      const int k = s*32 + q*8 + j;
      const float v = (m < 3) ? w3[k*3 + m] : 0.f;
      const u16 h = f2bf(v);
      fh[j] = (short)h; fl[j] = (short)f2bf(v - bf2f(h));
    }
    B3h[s] = fh; B3l[s] = fl;
  }

  for (int it = 0; it < iters; ++it) {
    const int base = (blockIdx.x * iters + it) << 8;   // 256 points / iteration

    // ---- phase A: per-thread fp32 encode -> bf16 feature row in LDS ----
    {
      const float2 xy = xq[base + tid];
      ((float2*)xyS)[tid] = xy;
      const float xf = xy.x, yf = xy.y;
      u32 er[16];
      #pragma unroll
      for (int l = 0; l < 16; ++l) {
        const int res = RESI[l];
        const float px = xf * (float)res, py = yf * (float)res;
        const float fx = floorf(px), fy = floorf(py);
        const float wx = px - fx, wy = py - fy;
        const u32 ix = (u32)fx, iy = (u32)fy;
        const float2* t = tab + (size_t)l * TBL;
        const float w00 = (1.f-wx)*(1.f-wy), w10 = wx*(1.f-wy);
        const float w01 = (1.f-wx)*wy,       w11 = wx*wy;
        float f0, f1;
        if (l < 12) {                                  // dense: paired 16B loads
          const u32 st  = (u32)res + 1u;
          const u32 i00 = ix + iy*st;
          const f32x4a eA = *(const f32x4a*)&t[i00];        // e00 | e10
          const f32x4a eB = *(const f32x4a*)&t[i00 + st];   // e01 | e11
          f0 = eA[0]*w00 + eA[2]*w10 + eB[0]*w01 + eB[2]*w11;
          f1 = eA[1]*w00 + eA[3]*w10 + eB[1]*w01 + eB[3]*w11;
        } else {                                       // spatial hash, u32 wraparound
          const u32 hy = iy * HPRIME, hy1 = hy + HPRIME;
          const u32 i00 = ( ix        ^ hy ) & TMASK;
          const u32 i10 = ((ix + 1u)  ^ hy ) & TMASK;
          const u32 i01 = ( ix        ^ hy1) & TMASK;
          const u32 i11 = ((ix + 1u)  ^ hy1) & TMASK;
          const float2 e00 = t[i00], e10 = t[i10], e01 = t[i01], e11 = t[i11];
          f0 = e00.x*w00 + e10.x*w10 + e01.x*w01 + e11.x*w11;
          f1 = e00.y*w00 + e10.y*w10 + e01.y*w01 + e11.y*w11;
        }
        er[l] = (u32)f2bf(f0) | ((u32)f2bf(f1) << 16);
      }
      uint4* rowp = (uint4*)&encS[tid * 40];
      rowp[0] = make_uint4(er[0],  er[1],  er[2],  er[3]);
      rowp[1] = make_uint4(er[4],  er[5],  er[6],  er[7]);
      rowp[2] = make_uint4(er[8],  er[9],  er[10], er[11]);
      rowp[3] = make_uint4(er[12], er[13], er[14], er[15]);
    }

    // ---- phase B: per-wave MFMA MLP, 4 tiles of 16 points (wave-private, no barriers) ----
    #pragma unroll 1
    for (int t4 = 0; t4 < 4; ++t4) {
      const int rbase = wv*64 + t4*16;
      const s16x8 a1 = *(const s16x8*)&encS[(rbase + m)*40 + q*8];

      float xr[4], yr[4];
      #pragma unroll
      for (int r = 0; r < 4; ++r) {
        const float2 v = ((const float2*)xyS)[rbase + q*4 + r];
        xr[r] = v.x; yr[r] = v.y;
      }

      f32x4 acc[4];
      #pragma unroll
      for (int c = 0; c < 4; ++c) {
        f32x4 z;
        #pragma unroll
        for (int r = 0; r < 4; ++r) z[r] = xr[r]*w1x[c] + yr[r]*w1y[c];  // fp32 x,y path
        acc[c] = MFMA(a1, B1[c], z);
      }

      u32* hw = &hS[wv][0];
      #pragma unroll
      for (int c = 0; c < 4; ++c)
        #pragma unroll
        for (int r = 0; r < 4; ++r) {
          const float h = fmaxf(acc[c][r], 0.f);
          const u16 hi = f2bf(h);
          const u16 lo = f2bf(h - bf2f(hi));
          hw[(q*4 + r)*68 + c*16 + m] = (u32)hi | ((u32)lo << 16);
        }

      uint4 r0 = *(uint4*)&hw[m*68 + q*8];
      uint4 r1 = *(uint4*)&hw[m*68 + q*8 + 4];
      uint4 r2 = *(uint4*)&hw[m*68 + 32 + q*8];
      uint4 r3 = *(uint4*)&hw[m*68 + 32 + q*8 + 4];
      u32x4 t0, t1;
      t0.x=plo(r0.x,r0.y); t0.y=plo(r0.z,r0.w); t0.z=plo(r1.x,r1.y); t0.w=plo(r1.z,r1.w);
      s16x8 hi0 = __builtin_bit_cast(s16x8, t0);
      t1.x=phi(r0.x,r0.y); t1.y=phi(r0.z,r0.w); t1.z=phi(r1.x,r1.y); t1.w=phi(r1.z,r1.w);
      s16x8 lo0 = __builtin_bit_cast(s16x8, t1);
      t0.x=plo(r2.x,r2.y); t0.y=plo(r2.z,r2.w); t0.z=plo(r3.x,r3.y); t0.w=plo(r3.z,r3.w);
      s16x8 hi1 = __builtin_bit_cast(s16x8, t0);
      t1.x=phi(r2.x,r2.y); t1.y=phi(r2.z,r2.w); t1.z=phi(r3.x,r3.y); t1.w=phi(r3.z,r3.w);
      s16x8 lo1 = __builtin_bit_cast(s16x8, t1);

      #pragma unroll
      for (int c = 0; c < 4; ++c) {
        f32x4 z = {0.f,0.f,0.f,0.f};
        z = MFMA(hi0, B2h[c][0], z); z = MFMA(hi1, B2h[c][1], z);
        z = MFMA(lo0, B2h[c][0], z); z = MFMA(lo1, B2h[c][1], z);
        z = MFMA(hi0, B2l[c][0], z); z = MFMA(hi1, B2l[c][1], z);
        acc[c] = z;
      }

      #pragma unroll
      for (int c = 0; c < 4; ++c)
        #pragma unroll
        for (int r = 0; r < 4; ++r) {
          const float h = fmaxf(acc[c][r], 0.f);
          const u16 hi = f2bf(h);
          const u16 lo = f2bf(h - bf2f(hi));
          hw[(q*4 + r)*68 + c*16 + m] = (u32)hi | ((u32)lo << 16);
        }

      r0 = *(uint4*)&hw[m*68 + q*8];
      r1 = *(uint4*)&hw[m*68 + q*8 + 4];
      r2 = *(uint4*)&hw[m*68 + 32 + q*8];
      r3 = *(uint4*)&hw[m*68 + 32 + q*8 + 4];
      t0.x=plo(r0.x,r0.y); t0.y=plo(r0.z,r0.w); t0.z=plo(r1.x,r1.y); t0.w=plo(r1.z,r1.w);
      hi0 = __builtin_bit_cast(s16x8, t0);
      t1.x=phi(r0.x,r0.y); t1.y=phi(r0.z,r0.w); t1.z=phi(r1.x,r1.y); t1.w=phi(r1.z,r1.w);
      lo0 = __builtin_bit_cast(s16x8, t1);
      t0.x=plo(r2.x,r2.y); t0.y=plo(r2.z,r2.w); t0.z=plo(r3.x,r3.y); t0.w=plo(r3.z,r3.w);
      hi1 = __builtin_bit_cast(s16x8, t0);
      t1.x=phi(r2.x,r2.y); t1.y=phi(r2.z,r2.w); t1.z=phi(r3.x,r3.y); t1.w=phi(r3.z,r3.w);
      lo1 = __builtin_bit_cast(s16x8, t1);

      f32x4 z = {0.f,0.f,0.f,0.f};
      z = MFMA(hi0, B3h[0], z); z = MFMA(hi1, B3h[1], z);
      z = MFMA(lo0, B3h[0], z); z = MFMA(lo1, B3h[1], z);
      z = MFMA(hi0, B3l[0], z); z = MFMA(hi1, B3l[1], z);

      if (m < 3) {   // C: row = q*4+r, col = m
        #pragma unroll
        for (int r = 0; r < 4; ++r)
          out[(size_t)(base + rbase + q*4 + r)*3 + m] = z[r];
      }
    }
  }
}

extern "C" void kernel_launch(void* const* d_in, const int* in_sizes, int n_in,
                              void* d_out, int out_size, void* d_ws, size_t ws_size,
                              hipStream_t stream) {
  const int N = in_sizes[0] / 2;            // 2^21 points
  const int ITERS = 4;
  const int blocks = N / (256 * ITERS);     // 2048 blocks
  ngp_fused<<<blocks, 256, 0, stream>>>(
      (const float2*)d_in[0], (const float2*)d_in[1],
      (const float*)d_in[2], (const float*)d_in[3], (const float*)d_in[4],
      (float*)d_out, ITERS);
}

// Round 6
// 467.484 us; speedup vs baseline: 1.9853x; 1.1399x over previous
//
#include <hip/hip_runtime.h>

typedef unsigned int u32;
typedef unsigned short u16;
typedef __attribute__((ext_vector_type(8))) short s16x8;
typedef __attribute__((ext_vector_type(4))) float f32x4;
typedef __attribute__((ext_vector_type(4))) unsigned int u32x4;
typedef float f32x4a __attribute__((ext_vector_type(4), aligned(8)));  // 8B-aligned 16B load
typedef u32  u32x2a  __attribute__((ext_vector_type(2), aligned(4)));  // 4B-aligned 8B load

#define TBL    524288u
#define TMASK  (TBL - 1u)
#define HPRIME 2654435761u

// res[l] = floor(16 * 1.3819^l); dense (linear) while (res+1)^2 <= 2^19 -> levels 0..11
__device__ constexpr int RESI[16] = {16,22,30,42,58,80,111,153,212,294,406,561,775,1072,1481,2047};

static __device__ __forceinline__ u16 f2bf(float f){            // RNE f32->bf16
  u32 u = __builtin_bit_cast(u32, f);
  return (u16)((u + 0x7fffu + ((u >> 16) & 1u)) >> 16);
}
static __device__ __forceinline__ float bf2f(u16 h){ return __builtin_bit_cast(float, (u32)h << 16); }
static __device__ __forceinline__ float blo(u32 e){ return __builtin_bit_cast(float, (u32)(e << 16)); }
static __device__ __forceinline__ float bhi(u32 e){ return __builtin_bit_cast(float, (u32)(e & 0xffff0000u)); }
static __device__ __forceinline__ u32 packbf2(float a, float b){ return (u32)f2bf(a) | ((u32)f2bf(b) << 16); }
static __device__ __forceinline__ u32 plo(u32 a, u32 b){ return (a & 0xffffu) | (b << 16); }
static __device__ __forceinline__ u32 phi(u32 a, u32 b){ return (a >> 16) | (b & 0xffff0000u); }

#define MFMA(A,B,C) __builtin_amdgcn_mfma_f32_16x16x32_bf16((A),(B),(C),0,0,0)

// R6 pre-pass: fp32 tables (64 MB) -> packed-bf16 tables (32 MB) in d_ws.
// Entries are |e|<=1e-4; bf16-rounding them changes features by <=2e-7 (they get
// bf16-rounded post-interp anyway). Halves gather bytes + line traffic; coarse/mid
// dense levels (~2.4 MB) become L2-resident per XCD.
__global__ __launch_bounds__(256) void cvt_tab(const float4* __restrict__ src,
                                               uint2* __restrict__ dst, int n4) {
  for (int i = blockIdx.x*256 + threadIdx.x; i < n4; i += gridDim.x*256) {
    const float4 v = src[i];
    dst[i] = make_uint2(packbf2(v.x, v.y), packbf2(v.z, v.w));
  }
}

// Fused instant-NGP: fp32 hash-grid encode (per-thread) + 34->64->64->3 MLP via bf16-split MFMA.
// x,y enter layer 1 through the fp32 C operand; layers 2/3 use hi/lo bf16 splits (~2^-17 rel err).
// All LDS regions are wave-private -> no __syncthreads anywhere.
// OCCUPANCY HISTORY (do not "optimize" blindly):
//   (256,2): VGPR 120, no spill, 515 us (R2) -> 443 us with paired dense loads (R5). KEEP.
//   (256,4): squeezed to 64 VGPR -> frag spills, WRITE 27->344 MB, 928 us (R3 - dead end)
//   (256,3): squeezed to 84 VGPR -> still spills, 795 us                 (R4 - dead end)
// ~120 arch VGPRs + AGPRs cap us at 2 blocks/CU; occupancy moves require a register
// restructure, not a launch-bounds tweak.
template<bool PACKED>
__global__ __launch_bounds__(256, 2) void ngp_fused(
    const float2* __restrict__ xq,    // [N] (x,y) fp32
    const float2* __restrict__ tab32, // [16*2^19] (f0,f1) fp32
    const u32*    __restrict__ ctab,  // [16*2^19] packed bf16 pair (d_ws) - PACKED path
    const float*  __restrict__ w1,    // [34][64]
    const float*  __restrict__ w2,    // [64][64]
    const float*  __restrict__ w3,    // [64][3]
    float* __restrict__ out,          // [N][3]
    int iters)
{
  __shared__ __align__(16) u16   encS[256 * 40];   // 32 bf16 features + 8 pad (80 B stride)
  __shared__ __align__(16) float xyS [256 * 2];    // fp32 x,y per point
  __shared__ __align__(16) u32   hS  [4][16 * 68]; // per-wave 16x64 (hi|lo) u32, stride 68 (+4 pad)

  const int tid  = threadIdx.x;
  const int lane = tid & 63;
  const int wv   = tid >> 6;
  const int m    = lane & 15;   // A row / B,C col
  const int q    = lane >> 4;   // k-quad

  // ---- build B-frags from global fp32 weights (one-time; L2-cached) ----
  float w1x[4], w1y[4];
  s16x8 B1[4], B2h[4][2], B2l[4][2], B3h[2], B3l[2];
  #pragma unroll
  for (int c = 0; c < 4; ++c) {
    const int n = c*16 + m;
    w1x[c] = w1[n]; w1y[c] = w1[64 + n];
    s16x8 f1;
    #pragma unroll
    for (int j = 0; j < 8; ++j) {               // B1: feature rows 2..33, K=32 exactly
      const int k = q*8 + j;
      f1[j] = (short)f2bf(w1[(2 + k)*64 + n]);
    }
    B1[c] = f1;
    #pragma unroll
    for (int s = 0; s < 2; ++s) {
      s16x8 fh, fl;
      #pragma unroll
      for (int j = 0; j < 8; ++j) {
        const int k = s*32 + q*8 + j;
        const float v = w2[k*64 + n];
        const u16 h = f2bf(v);
        fh[j] = (short)h; fl[j] = (short)f2bf(v - bf2f(h));
      }
      B2h[c][s] = fh; B2l[c][s] = fl;
    }
  }
  #pragma unroll
  for (int s = 0; s < 2; ++s) {
    s16x8 fh, fl;
    #pragma unroll
    for (int j = 0; j < 8; ++j) {
      const int k = s*32 + q*8 + j;
      const float v = (m < 3) ? w3[k*3 + m] : 0.f;
      const u16 h = f2bf(v);
      fh[j] = (short)h; fl[j] = (short)f2bf(v - bf2f(h));
    }
    B3h[s] = fh; B3l[s] = fl;
  }

  for (int it = 0; it < iters; ++it) {
    const int base = (blockIdx.x * iters + it) << 8;   // 256 points / iteration

    // ---- phase A: per-thread fp32 encode -> bf16 feature row in LDS ----
    {
      const float2 xy = xq[base + tid];
      ((float2*)xyS)[tid] = xy;
      const float xf = xy.x, yf = xy.y;
      u32 er[16];
      #pragma unroll
      for (int l = 0; l < 16; ++l) {
        const int res = RESI[l];
        const float px = xf * (float)res, py = yf * (float)res;
        const float fx = floorf(px), fy = floorf(py);
        const float wx = px - fx, wy = py - fy;
        const u32 ix = (u32)fx, iy = (u32)fy;
        const float w00 = (1.f-wx)*(1.f-wy), w10 = wx*(1.f-wy);
        const float w01 = (1.f-wx)*wy,       w11 = wx*wy;
        float f0, f1;
        if (l < 12) {                                  // dense: paired corner loads
          const u32 st  = (u32)res + 1u;
          const u32 i00 = ix + iy*st;
          if (PACKED) {
            const u32* t = ctab + (size_t)l * TBL;
            const u32x2a eA = *(const u32x2a*)&t[i00];        // e00 | e10
            const u32x2a eB = *(const u32x2a*)&t[i00 + st];   // e01 | e11
            f0 = blo(eA[0])*w00 + blo(eA[1])*w10 + blo(eB[0])*w01 + blo(eB[1])*w11;
            f1 = bhi(eA[0])*w00 + bhi(eA[1])*w10 + bhi(eB[0])*w01 + bhi(eB[1])*w11;
          } else {
            const float2* t = tab32 + (size_t)l * TBL;
            const f32x4a eA = *(const f32x4a*)&t[i00];        // e00 | e10
            const f32x4a eB = *(const f32x4a*)&t[i00 + st];   // e01 | e11
            f0 = eA[0]*w00 + eA[2]*w10 + eB[0]*w01 + eB[2]*w11;
            f1 = eA[1]*w00 + eA[3]*w10 + eB[1]*w01 + eB[3]*w11;
          }
        } else {                                       // spatial hash, u32 wraparound
          const u32 hy = iy * HPRIME, hy1 = hy + HPRIME;
          const u32 i00 = ( ix        ^ hy ) & TMASK;
          const u32 i10 = ((ix + 1u)  ^ hy ) & TMASK;
          const u32 i01 = ( ix        ^ hy1) & TMASK;
          const u32 i11 = ((ix + 1u)  ^ hy1) & TMASK;
          if (PACKED) {
            const u32* t = ctab + (size_t)l * TBL;
            const u32 e00 = t[i00], e10 = t[i10], e01 = t[i01], e11 = t[i11];
            f0 = blo(e00)*w00 + blo(e10)*w10 + blo(e01)*w01 + blo(e11)*w11;
            f1 = bhi(e00)*w00 + bhi(e10)*w10 + bhi(e01)*w01 + bhi(e11)*w11;
          } else {
            const float2* t = tab32 + (size_t)l * TBL;
            const float2 e00 = t[i00], e10 = t[i10], e01 = t[i01], e11 = t[i11];
            f0 = e00.x*w00 + e10.x*w10 + e01.x*w01 + e11.x*w11;
            f1 = e00.y*w00 + e10.y*w10 + e01.y*w01 + e11.y*w11;
          }
        }
        er[l] = (u32)f2bf(f0) | ((u32)f2bf(f1) << 16);
      }
      uint4* rowp = (uint4*)&encS[tid * 40];
      rowp[0] = make_uint4(er[0],  er[1],  er[2],  er[3]);
      rowp[1] = make_uint4(er[4],  er[5],  er[6],  er[7]);
      rowp[2] = make_uint4(er[8],  er[9],  er[10], er[11]);
      rowp[3] = make_uint4(er[12], er[13], er[14], er[15]);
    }

    // ---- phase B: per-wave MFMA MLP, 4 tiles of 16 points (wave-private, no barriers) ----
    #pragma unroll 1
    for (int t4 = 0; t4 < 4; ++t4) {
      const int rbase = wv*64 + t4*16;
      const s16x8 a1 = *(const s16x8*)&encS[(rbase + m)*40 + q*8];

      float xr[4], yr[4];
      #pragma unroll
      for (int r = 0; r < 4; ++r) {
        const float2 v = ((const float2*)xyS)[rbase + q*4 + r];
        xr[r] = v.x; yr[r] = v.y;
      }

      f32x4 acc[4];
      #pragma unroll
      for (int c = 0; c < 4; ++c) {
        f32x4 z;
        #pragma unroll
        for (int r = 0; r < 4; ++r) z[r] = xr[r]*w1x[c] + yr[r]*w1y[c];  // fp32 x,y path
        acc[c] = MFMA(a1, B1[c], z);
      }

      u32* hw = &hS[wv][0];
      #pragma unroll
      for (int c = 0; c < 4; ++c)
        #pragma unroll
        for (int r = 0; r < 4; ++r) {
          const float h = fmaxf(acc[c][r], 0.f);
          const u16 hi = f2bf(h);
          const u16 lo = f2bf(h - bf2f(hi));
          hw[(q*4 + r)*68 + c*16 + m] = (u32)hi | ((u32)lo << 16);
        }

      uint4 r0 = *(uint4*)&hw[m*68 + q*8];
      uint4 r1 = *(uint4*)&hw[m*68 + q*8 + 4];
      uint4 r2 = *(uint4*)&hw[m*68 + 32 + q*8];
      uint4 r3 = *(uint4*)&hw[m*68 + 32 + q*8 + 4];
      u32x4 t0, t1;
      t0.x=plo(r0.x,r0.y); t0.y=plo(r0.z,r0.w); t0.z=plo(r1.x,r1.y); t0.w=plo(r1.z,r1.w);
      s16x8 hi0 = __builtin_bit_cast(s16x8, t0);
      t1.x=phi(r0.x,r0.y); t1.y=phi(r0.z,r0.w); t1.z=phi(r1.x,r1.y); t1.w=phi(r1.z,r1.w);
      s16x8 lo0 = __builtin_bit_cast(s16x8, t1);
      t0.x=plo(r2.x,r2.y); t0.y=plo(r2.z,r2.w); t0.z=plo(r3.x,r3.y); t0.w=plo(r3.z,r3.w);
      s16x8 hi1 = __builtin_bit_cast(s16x8, t0);
      t1.x=phi(r2.x,r2.y); t1.y=phi(r2.z,r2.w); t1.z=phi(r3.x,r3.y); t1.w=phi(r3.z,r3.w);
      s16x8 lo1 = __builtin_bit_cast(s16x8, t1);

      #pragma unroll
      for (int c = 0; c < 4; ++c) {
        f32x4 z = {0.f,0.f,0.f,0.f};
        z = MFMA(hi0, B2h[c][0], z); z = MFMA(hi1, B2h[c][1], z);
        z = MFMA(lo0, B2h[c][0], z); z = MFMA(lo1, B2h[c][1], z);
        z = MFMA(hi0, B2l[c][0], z); z = MFMA(hi1, B2l[c][1], z);
        acc[c] = z;
      }

      #pragma unroll
      for (int c = 0; c < 4; ++c)
        #pragma unroll
        for (int r = 0; r < 4; ++r) {
          const float h = fmaxf(acc[c][r], 0.f);
          const u16 hi = f2bf(h);
          const u16 lo = f2bf(h - bf2f(hi));
          hw[(q*4 + r)*68 + c*16 + m] = (u32)hi | ((u32)lo << 16);
        }

      r0 = *(uint4*)&hw[m*68 + q*8];
      r1 = *(uint4*)&hw[m*68 + q*8 + 4];
      r2 = *(uint4*)&hw[m*68 + 32 + q*8];
      r3 = *(uint4*)&hw[m*68 + 32 + q*8 + 4];
      t0.x=plo(r0.x,r0.y); t0.y=plo(r0.z,r0.w); t0.z=plo(r1.x,r1.y); t0.w=plo(r1.z,r1.w);
      hi0 = __builtin_bit_cast(s16x8, t0);
      t1.x=phi(r0.x,r0.y); t1.y=phi(r0.z,r0.w); t1.z=phi(r1.x,r1.y); t1.w=phi(r1.z,r1.w);
      lo0 = __builtin_bit_cast(s16x8, t1);
      t0.x=plo(r2.x,r2.y); t0.y=plo(r2.z,r2.w); t0.z=plo(r3.x,r3.y); t0.w=plo(r3.z,r3.w);
      hi1 = __builtin_bit_cast(s16x8, t0);
      t1.x=phi(r2.x,r2.y); t1.y=phi(r2.z,r2.w); t1.z=phi(r3.x,r3.y); t1.w=phi(r3.z,r3.w);
      lo1 = __builtin_bit_cast(s16x8, t1);

      f32x4 z = {0.f,0.f,0.f,0.f};
      z = MFMA(hi0, B3h[0], z); z = MFMA(hi1, B3h[1], z);
      z = MFMA(lo0, B3h[0], z); z = MFMA(lo1, B3h[1], z);
      z = MFMA(hi0, B3l[0], z); z = MFMA(hi1, B3l[1], z);

      if (m < 3) {   // C: row = q*4+r, col = m
        #pragma unroll
        for (int r = 0; r < 4; ++r)
          out[(size_t)(base + rbase + q*4 + r)*3 + m] = z[r];
      }
    }
  }
}

extern "C" void kernel_launch(void* const* d_in, const int* in_sizes, int n_in,
                              void* d_out, int out_size, void* d_ws, size_t ws_size,
                              hipStream_t stream) {
  const int N = in_sizes[0] / 2;            // 2^21 points
  const int ITERS = 4;
  const int blocks = N / (256 * ITERS);     // 2048 blocks
  const size_t ctab_bytes = (size_t)16 * TBL * 4;   // 32 MB packed-bf16 tables
  if (ws_size >= ctab_bytes) {
    cvt_tab<<<2048, 256, 0, stream>>>((const float4*)d_in[1], (uint2*)d_ws, (int)(16*TBL/2));
    ngp_fused<true><<<blocks, 256, 0, stream>>>(
        (const float2*)d_in[0], (const float2*)d_in[1], (const u32*)d_ws,
        (const float*)d_in[2], (const float*)d_in[3], (const float*)d_in[4],
        (float*)d_out, ITERS);
  } else {
    ngp_fused<false><<<blocks, 256, 0, stream>>>(
        (const float2*)d_in[0], (const float2*)d_in[1], (const u32*)d_ws,
        (const float*)d_in[2], (const float*)d_in[3], (const float*)d_in[4],
        (float*)d_out, ITERS);
  }
}